// Round 12
// baseline (1205.641 us; speedup 1.0000x reference)
//
#include <hip/hip_runtime.h>
#include <stdint.h>

#define NN 50000
#define NE 400000
#define EMB 384
#define NH 768
#define NL 5

typedef __bf16 bf16x8_t __attribute__((ext_vector_type(8)));
typedef float  f32x4_t  __attribute__((ext_vector_type(4)));

__device__ __forceinline__ float bflo(uint32_t u){ union{uint32_t u;float f;} v; v.u = u<<16; return v.f; }
__device__ __forceinline__ float bfhi(uint32_t u){ union{uint32_t u;float f;} v; v.u = u & 0xffff0000u; return v.f; }
__device__ __forceinline__ uint16_t f2bf(float f){
  union{float f;uint32_t u;} v; v.f=f;
  uint32_t r = v.u + 0x7fffu + ((v.u>>16)&1u);
  return (uint16_t)(r>>16);
}
__device__ __forceinline__ uint32_t bfpack2(float a, float b){
  return (uint32_t)f2bf(a) | ((uint32_t)f2bf(b)<<16);
}
// hardware packed f32->bf16 (RTNE), 1 instruction for 2 elements — hot paths only
__device__ __forceinline__ uint32_t bfpack2h(float a, float b){
  uint32_t r;
  asm("v_cvt_pk_bf16_f32 %0, %1, %2" : "=v"(r) : "v"(a), "v"(b));
  return r;
}
__device__ __forceinline__ bf16x8_t as_bf16x8(uint4 u){
  union{uint4 a; bf16x8_t b;} c; c.a = u; return c.b;
}

// async global->LDS DMA, 16B per lane. LDS dest must be wave-uniform base + lane*16.
__device__ __forceinline__ void gld16(uint16_t* ldsp, const uint16_t* gp){
  __builtin_amdgcn_global_load_lds(
      (const __attribute__((address_space(1))) uint32_t*)gp,
      (__attribute__((address_space(3))) uint32_t*)ldsp,
      16, 0, 0);
}

// ---------------- CSR build ----------------
__global__ void hist_kernel(const int* __restrict__ dst, int* __restrict__ count){
  int i = blockIdx.x*256 + threadIdx.x;
  if (i < NE) atomicAdd(&count[dst[i]], 1);
}
__global__ void scan_block_sum(const int* __restrict__ count, int* __restrict__ bsum, int n){
  __shared__ int s[256];
  int i = blockIdx.x*256 + threadIdx.x;
  s[threadIdx.x] = (i<n) ? count[i] : 0;
  __syncthreads();
  for (int st=128; st>0; st>>=1){
    if (threadIdx.x < st) s[threadIdx.x] += s[threadIdx.x+st];
    __syncthreads();
  }
  if (threadIdx.x==0) bsum[blockIdx.x] = s[0];
}
__global__ void scan_excl_small(int* __restrict__ bsum, int nb){
  __shared__ int s[256];
  int t = threadIdx.x;
  int v = (t<nb) ? bsum[t] : 0;
  s[t] = v;
  __syncthreads();
  for (int st=1; st<256; st<<=1){
    int u = (t>=st) ? s[t-st] : 0;
    __syncthreads();
    s[t] += u;
    __syncthreads();
  }
  if (t<nb) bsum[t] = s[t] - v;
}
__global__ void scan_final(const int* __restrict__ count, const int* __restrict__ bsum,
                           int* __restrict__ rowptr, int* __restrict__ cursor, int n){
  __shared__ int s[256];
  int t = threadIdx.x;
  int i = blockIdx.x*256 + t;
  int v = (i<n) ? count[i] : 0;
  s[t] = v;
  __syncthreads();
  for (int st=1; st<256; st<<=1){
    int u = (t>=st) ? s[t-st] : 0;
    __syncthreads();
    s[t] += u;
    __syncthreads();
  }
  int off = bsum[blockIdx.x] + s[t] - v;
  if (i < n){
    rowptr[i] = off; cursor[i] = off;
    if (i == n-1) rowptr[n] = off + v;
  }
}
__global__ void scatter_kernel(const int* __restrict__ dst, const int* __restrict__ src,
                               const int* __restrict__ eattr, int* __restrict__ cursor,
                               int* __restrict__ csr_src, int* __restrict__ csr_code){
  int e = blockIdx.x*256 + threadIdx.x;
  if (e < NE){
    int p = atomicAdd(&cursor[dst[e]], 1);
    csr_src[p] = src[e];
    csr_code[p] = eattr[e*3] | (eattr[e*3+1]<<3) | (eattr[e*3+2]<<6);
  }
}

// ---------------- bond-sum table ----------------
__global__ void build_bond(const float* __restrict__ bemb, uint16_t* __restrict__ bt){
  const int code = blockIdx.x;            // 512
  const int t0 = code&7, t1=(code>>3)&7, t2=code>>6;
  const int c = threadIdx.x;              // 192 threads x 2 floats
  const float2 a = ((const float2*)(bemb + (size_t)( 0+t0)*EMB))[c];
  const float2 b = ((const float2*)(bemb + (size_t)( 8+t1)*EMB))[c];
  const float2 d = ((const float2*)(bemb + (size_t)(16+t2)*EMB))[c];
  ((uint32_t*)(bt + (size_t)code*EMB))[c] = bfpack2(a.x+b.x+d.x, a.y+b.y+d.y);
}

// ---------------- weight transpose + f32->bf16 ----------------
__global__ void transpose_w(const float* __restrict__ in, uint16_t* __restrict__ outp,
                            int R, int Cc){
  __shared__ float tile[32][33];
  const size_t lo = (size_t)blockIdx.z * R * Cc;
  int cb = blockIdx.x*32, rb = blockIdx.y*32;
  int r = rb + threadIdx.y, c = cb + threadIdx.x;
  if (r < R && c < Cc) tile[threadIdx.y][threadIdx.x] = in[lo + (size_t)r*Cc + c];
  __syncthreads();
  int orr = cb + threadIdx.y, occ = rb + threadIdx.x;
  if (orr < Cc && occ < R) outp[lo + (size_t)orr*R + occ] = f2bf(tile[threadIdx.x][threadIdx.y]);
}

// ---------------- atom encoder ----------------
__global__ __launch_bounds__(256) void atom_encode(
    const int* __restrict__ x, const float* __restrict__ aemb,
    uint16_t* __restrict__ h){
  const int w = threadIdx.x >> 6, lane = threadIdx.x & 63;
  const int i = blockIdx.x*4 + w;
  if (i >= NN) return;
  float a0=0,a1=0,a2=0,a3=0,a4=0,a5=0;
  #pragma unroll
  for (int k=0;k<9;k++){
    const int idx = x[i*9+k];
    const float2* p = (const float2*)(aemb + ((size_t)(k*64+idx))*EMB) + lane*3;
    float2 u0=p[0], u1=p[1], u2=p[2];
    a0+=u0.x; a1+=u0.y; a2+=u1.x; a3+=u1.y; a4+=u2.x; a5+=u2.y;
  }
  uint32_t* hp = (uint32_t*)(h + (size_t)i*EMB) + lane*3;
  hp[0]=bfpack2(a0,a1); hp[1]=bfpack2(a2,a3); hp[2]=bfpack2(a4,a5);
}

// ---------------- aggregation (static: one wave per node) ----------------
template<int BNREL>
__global__ __launch_bounds__(256) void agg_kernel(
    const uint16_t* __restrict__ in, const uint16_t* __restrict__ bondt,
    const float* __restrict__ scale, const float* __restrict__ shift,
    const int* __restrict__ rowptr, const int* __restrict__ csr_src,
    const int* __restrict__ csr_code, uint16_t* __restrict__ za){
  const int w = threadIdx.x >> 6, lane = threadIdx.x & 63;
  const int i = blockIdx.x*4 + w;
  if (i >= NN) return;

  float sc0=0,sc1=0,sc2=0,sc3=0,sc4=0,sc5=0, sh0=0,sh1=0,sh2=0,sh3=0,sh4=0,sh5=0;
  if (BNREL){
    const int c = lane*6;
    sc0=scale[c]; sc1=scale[c+1]; sc2=scale[c+2]; sc3=scale[c+3]; sc4=scale[c+4]; sc5=scale[c+5];
    sh0=shift[c]; sh1=shift[c+1]; sh2=shift[c+2]; sh3=shift[c+3]; sh4=shift[c+4]; sh5=shift[c+5];
  }

  const uint32_t* hs = (const uint32_t*)(in + (size_t)i*EMB) + lane*3;
  uint32_t s0=hs[0], s1=hs[1], s2=hs[2];
  float a0,a1,a2,a3,a4,a5;
  if (BNREL){
    a0 = fmaxf(bflo(s0)*sc0+sh0, 0.f); a1 = fmaxf(bfhi(s0)*sc1+sh1, 0.f);
    a2 = fmaxf(bflo(s1)*sc2+sh2, 0.f); a3 = fmaxf(bfhi(s1)*sc3+sh3, 0.f);
    a4 = fmaxf(bflo(s2)*sc4+sh4, 0.f); a5 = fmaxf(bfhi(s2)*sc5+sh5, 0.f);
  } else {
    a0 = bflo(s0); a1 = bfhi(s0); a2 = bflo(s1); a3 = bfhi(s1); a4 = bflo(s2); a5 = bfhi(s2);
  }

  const int rs = rowptr[i], re = rowptr[i+1];
  int k = rs;
  for (; k + 4 <= re; k += 4){
    int sj[4], cj[4];
    #pragma unroll
    for (int j=0;j<4;j++){ sj[j]=csr_src[k+j]; cj[j]=csr_code[k+j]; }
    uint32_t u[4][3], b[4][3];
    #pragma unroll
    for (int j=0;j<4;j++){
      const uint32_t* hp = (const uint32_t*)(in + (size_t)sj[j]*EMB) + lane*3;
      u[j][0]=hp[0]; u[j][1]=hp[1]; u[j][2]=hp[2];
      const uint32_t* bp = (const uint32_t*)(bondt + (size_t)cj[j]*EMB) + lane*3;
      b[j][0]=bp[0]; b[j][1]=bp[1]; b[j][2]=bp[2];
    }
    #pragma unroll
    for (int j=0;j<4;j++){
      float v0,v1,v2,v3,v4,v5;
      if (BNREL){
        v0 = fmaxf(bflo(u[j][0])*sc0+sh0, 0.f); v1 = fmaxf(bfhi(u[j][0])*sc1+sh1, 0.f);
        v2 = fmaxf(bflo(u[j][1])*sc2+sh2, 0.f); v3 = fmaxf(bfhi(u[j][1])*sc3+sh3, 0.f);
        v4 = fmaxf(bflo(u[j][2])*sc4+sh4, 0.f); v5 = fmaxf(bfhi(u[j][2])*sc5+sh5, 0.f);
      } else {
        v0=bflo(u[j][0]); v1=bfhi(u[j][0]); v2=bflo(u[j][1]);
        v3=bfhi(u[j][1]); v4=bflo(u[j][2]); v5=bfhi(u[j][2]);
      }
      a0 += fmaxf(v0+bflo(b[j][0]), 0.f); a1 += fmaxf(v1+bfhi(b[j][0]), 0.f);
      a2 += fmaxf(v2+bflo(b[j][1]), 0.f); a3 += fmaxf(v3+bfhi(b[j][1]), 0.f);
      a4 += fmaxf(v4+bflo(b[j][2]), 0.f); a5 += fmaxf(v5+bfhi(b[j][2]), 0.f);
    }
  }
  for (; k < re; k++){
    const int s = csr_src[k];
    const int code = csr_code[k];
    const uint32_t* hp = (const uint32_t*)(in + (size_t)s*EMB) + lane*3;
    uint32_t u0=hp[0], u1=hp[1], u2=hp[2];
    const uint32_t* bp = (const uint32_t*)(bondt + (size_t)code*EMB) + lane*3;
    uint32_t b0=bp[0], b1=bp[1], b2=bp[2];
    float v0,v1,v2,v3,v4,v5;
    if (BNREL){
      v0 = fmaxf(bflo(u0)*sc0+sh0, 0.f); v1 = fmaxf(bfhi(u0)*sc1+sh1, 0.f);
      v2 = fmaxf(bflo(u1)*sc2+sh2, 0.f); v3 = fmaxf(bfhi(u1)*sc3+sh3, 0.f);
      v4 = fmaxf(bflo(u2)*sc4+sh4, 0.f); v5 = fmaxf(bfhi(u2)*sc5+sh5, 0.f);
    } else {
      v0=bflo(u0); v1=bfhi(u0); v2=bflo(u1); v3=bfhi(u1); v4=bflo(u2); v5=bfhi(u2);
    }
    a0 += fmaxf(v0+bflo(b0), 0.f); a1 += fmaxf(v1+bfhi(b0), 0.f);
    a2 += fmaxf(v2+bflo(b1), 0.f); a3 += fmaxf(v3+bfhi(b1), 0.f);
    a4 += fmaxf(v4+bflo(b2), 0.f); a5 += fmaxf(v5+bfhi(b2), 0.f);
  }

  uint32_t* zp = (uint32_t*)(za + (size_t)i*EMB) + lane*3;
  zp[0] = bfpack2(a0,a1);
  zp[1] = bfpack2(a2,a3);
  zp[2] = bfpack2(a4,a5);
}

// ---------------- GEMM: r8 structure + 3-buffer counted-vmcnt pipeline (T4) ----------------
// r8 = best measured (1128 µs, 64.5 µs/GEMM). Its __syncthreads drains vmcnt(0) including
// the next part's DMAs issued ~300cy earlier -> ~600cy un-hidden latency per part. Fix:
// THREE panel buffers; stage part p+2 in part p; raw s_barrier + counted vmcnt.
// Ledger (program order pinned by sched_barrier(0) around stageB):
//   part p body: [vmcnt(N); s_barrier; SB; stageB((p+2)%3)x4; SB; dostep x2 (4 A-loads)]
//   queue at part p's wait: stage(p)x4 | A(p-2)x4, stage(p+1)x4, A(p-1)x4 -> 12 after ->
//   vmcnt(12); last part: only A x8 after -> vmcnt(8). Prologue syncthreads fully drains
//   parts 0/1 so their waits are trivially satisfied.
//   Overwrite safety: stage(p+2) targets buf read in part p-1; barrier(p) ensures done. ✓
//   Barrier safety: brow-exit is block-uniform; every wave reaches every s_barrier. ✓
// A prefetch = r8's depth-2 named scalars (VGPR unchanged -> no spill; WRITE marker must
// stay exactly 77346/38673). LDS: GEMM1 ~50KB (3 blocks/CU), GEMM2 ~56KB (2 blocks/CU,
// equal to its measured r8 residency).
template<int BNA, int KK>
__global__ __launch_bounds__(256, 2) void gemm_bt(
    const uint16_t* __restrict__ A, const uint16_t* __restrict__ Bt,
    const float* __restrict__ bias, const float* __restrict__ scA,
    const float* __restrict__ shA, uint16_t* __restrict__ C,
    float* __restrict__ stats, int M, int N, int nbr){
  constexpr int NK = KK/32;        // 12 or 24 kq steps
  constexpr int NPART = NK/2;      // 6 or 12 parts of 64-K
  __shared__ __align__(16) uint16_t panel[3][1024*8];   // 3 x 16KB: slot gidx = 16B
  __shared__ float sAs[BNA ? KK : 1];
  __shared__ float hAs[BNA ? KK : 1];
  __shared__ float csum[128];
  __shared__ float csq[128];

  const int tid = threadIdx.x;
  const int nbc = N >> 7;
  const int xcd = blockIdx.x & 7;
  const int slot = blockIdx.x >> 3;
  const int bcol = slot % nbc;
  const int brow = (slot / nbc)*8 + xcd;
  if (brow >= nbr) return;
  const int rowbase = brow << 7;

  const int lane = tid & 63;
  const int w = tid >> 6;
  const int quad = lane >> 4, l16 = lane & 15;
  const int bcol128 = bcol*128;

  // A per-lane rows: wave w owns rows w*32..+31; frag mi adds 16
  int rowA0 = rowbase + w*32 + l16;      if (rowA0 >= M) rowA0 = M-1;
  int rowA1 = rowbase + w*32 + 16 + l16; if (rowA1 >= M) rowA1 = M-1;
  const uint16_t* gA0 = A + (size_t)rowA0*KK + quad*8;
  const uint16_t* gA1 = A + (size_t)rowA1*KK + quad*8;

  if (BNA){
    for (int i = tid; i < KK; i += 256){ sAs[i] = scA[i]; hAs[i] = shA[i]; }
  }

  // coalesced pre-swizzled DMA: slot gidx <- Bt[col=gidx>>3][k0 + ((gidx&7)^((gidx>>5)&7))*8]
  auto stageB = [&](int buf, int k0){
    #pragma unroll
    for (int c = 0; c < 4; ++c){
      const int gidx = c*256 + tid;
      const int col  = gidx >> 3;
      const int k8   = (gidx & 7) ^ ((gidx >> 5) & 7);
      gld16(&panel[buf][(size_t)gidx*8],
            Bt + (size_t)(bcol128 + col)*KK + k0 + k8*8);
    }
  };
  // BN+ReLU transform of an A fragment (in-register, off all sync paths)
  auto xf = [&](uint4 ca, int kq)->bf16x8_t{
    const int kb = kq*32 + quad*8;
    float4 sv0 = *(const float4*)&sAs[kb];
    float4 sv1 = *(const float4*)&sAs[kb+4];
    float4 hv0 = *(const float4*)&hAs[kb];
    float4 hv1 = *(const float4*)&hAs[kb+4];
    float e0,e1,e2,e3,e4,e5,e6,e7;
    e0=fmaxf(bflo(ca.x)*sv0.x+hv0.x,0.f); e1=fmaxf(bfhi(ca.x)*sv0.y+hv0.y,0.f);
    e2=fmaxf(bflo(ca.y)*sv0.z+hv0.z,0.f); e3=fmaxf(bfhi(ca.y)*sv0.w+hv0.w,0.f);
    e4=fmaxf(bflo(ca.z)*sv1.x+hv1.x,0.f); e5=fmaxf(bfhi(ca.z)*sv1.y+hv1.y,0.f);
    e6=fmaxf(bflo(ca.w)*sv1.z+hv1.z,0.f); e7=fmaxf(bfhi(ca.w)*sv1.w+hv1.w,0.f);
    return as_bf16x8(make_uint4(bfpack2h(e0,e1),bfpack2h(e2,e3),bfpack2h(e4,e5),bfpack2h(e6,e7)));
  };

  f32x4_t acc[2][2][4];
  #pragma unroll
  for (int mi=0;mi<2;mi++)
    #pragma unroll
    for (int g=0;g<2;g++)
      #pragma unroll
      for (int nj=0;nj<4;nj++)
        acc[mi][g][nj] = (f32x4_t){0.f,0.f,0.f,0.f};

  auto mf = [&](int buf, int s, bf16x8_t fa0, bf16x8_t fa1){
    const int lx = (s*4 + quad) ^ (l16 & 7);
    #pragma unroll
    for (int g=0; g<2; ++g)
      #pragma unroll
      for (int nj=0; nj<4; ++nj){
        const int col = g*64 + l16*4 + nj;
        bf16x8_t fb = *(const bf16x8_t*)&panel[buf][(size_t)(col*8 + lx)*8];
        acc[0][g][nj] = __builtin_amdgcn_mfma_f32_16x16x32_bf16(fa0, fb, acc[0][g][nj], 0,0,0);
        acc[1][g][nj] = __builtin_amdgcn_mfma_f32_16x16x32_bf16(fa1, fb, acc[1][g][nj], 0,0,0);
      }
  };
  // one kq sub-step: consume a named A pair, reload it for kq+2 (r8 depth-2)
  auto dostep = [&](int kq, int buf, uint4& x0, uint4& x1){
    bf16x8_t fa0 = BNA ? xf(x0, kq) : as_bf16x8(x0);
    bf16x8_t fa1 = BNA ? xf(x1, kq) : as_bf16x8(x1);
    if (kq + 2 < NK){
      x0 = *(const uint4*)(gA0 + (kq+2)*32);
      x1 = *(const uint4*)(gA1 + (kq+2)*32);
    }
    mf(buf, kq & 1, fa0, fa1);
  };

  // ---- prologue: DMA parts 0 and 1; A kq0/kq1 into named scalars; full drain ----
  stageB(0, 0);
  if (NPART > 1) stageB(1, 64);
  uint4 a0c = *(const uint4*)(gA0);
  uint4 a1c = *(const uint4*)(gA1);
  uint4 a0n = *(const uint4*)(gA0 + 32);
  uint4 a1n = *(const uint4*)(gA1 + 32);
  __syncthreads();                        // panels 0,1 + sAs ready; vmcnt queue empty

  for (int p = 0; p < NPART; ++p){
    // counted wait: ensure part p's 4 DMAs retired (12 ops after them in steady state)
    if (p == NPART-1) asm volatile("s_waitcnt vmcnt(8)" ::: "memory");
    else              asm volatile("s_waitcnt vmcnt(12)" ::: "memory");
    __builtin_amdgcn_s_barrier();
    __builtin_amdgcn_sched_barrier(0);
    if (p + 2 < NPART) stageB((p+2)%3, (p+2)*64);   // distance-2: ~2 parts of cover
    __builtin_amdgcn_sched_barrier(0);              // pin stage before A-loads (count ledger)
    dostep(2*p,     p%3, a0c, a1c);
    dostep(2*p + 1, p%3, a0n, a1n);
  }

  __syncthreads();
  if (tid < 128){ csum[tid]=0.f; csq[tid]=0.f; }
  __syncthreads();

  const int colbase = bcol128 + l16*4;
  float bv[2][4], ssum[2][4], sq[2][4];
  #pragma unroll
  for (int g=0;g<2;g++)
    #pragma unroll
    for (int nj=0;nj<4;nj++){
      bv[g][nj] = bias[colbase + g*64 + nj];
      ssum[g][nj] = 0.f; sq[g][nj] = 0.f;
    }

  #pragma unroll
  for (int mi=0;mi<2;mi++){
    #pragma unroll
    for (int r=0;r<4;r++){
      const int grow = rowbase + w*32 + mi*16 + quad*4 + r;
      if (grow < M){
        #pragma unroll
        for (int g=0;g<2;g++){
          float v0 = acc[mi][g][0][r] + bv[g][0];
          float v1 = acc[mi][g][1][r] + bv[g][1];
          float v2 = acc[mi][g][2][r] + bv[g][2];
          float v3 = acc[mi][g][3][r] + bv[g][3];
          uint2 pk = make_uint2(bfpack2h(v0,v1), bfpack2h(v2,v3));
          *(uint2*)(C + (size_t)grow*N + colbase + g*64) = pk;
          ssum[g][0]+=v0; ssum[g][1]+=v1; ssum[g][2]+=v2; ssum[g][3]+=v3;
          sq[g][0]+=v0*v0; sq[g][1]+=v1*v1; sq[g][2]+=v2*v2; sq[g][3]+=v3*v3;
        }
      }
    }
  }
  #pragma unroll
  for (int g=0;g<2;g++)
    #pragma unroll
    for (int nj=0;nj<4;nj++){
      ssum[g][nj] += __shfl_xor(ssum[g][nj], 16); ssum[g][nj] += __shfl_xor(ssum[g][nj], 32);
      sq[g][nj]   += __shfl_xor(sq[g][nj],   16); sq[g][nj]   += __shfl_xor(sq[g][nj],   32);
    }
  if (quad == 0){
    #pragma unroll
    for (int g=0;g<2;g++)
      #pragma unroll
      for (int nj=0;nj<4;nj++){
        atomicAdd(&csum[g*64 + l16*4 + nj], ssum[g][nj]);
        atomicAdd(&csq [g*64 + l16*4 + nj], sq[g][nj]);
      }
  }
  __syncthreads();
  if (tid < 128){
    atomicAdd(&stats[bcol128 + tid], csum[tid]);
    atomicAdd(&stats[N + bcol128 + tid], csq[tid]);
  }
}

// ---------------- BN finalize (self-clearing) ----------------
__global__ void bn_finalize(float* __restrict__ stats, const float* __restrict__ gamma,
                            const float* __restrict__ beta, float* __restrict__ scale,
                            float* __restrict__ shift, int n, float invM){
  int c = blockIdx.x*256 + threadIdx.x;
  if (c < n){
    float mean = stats[c]*invM;
    float var  = stats[n+c]*invM - mean*mean;
    float sc = gamma[c] * rsqrtf(var + 1e-5f);
    scale[c] = sc;
    shift[c] = beta[c] - mean*sc;
    stats[c] = 0.f;
    stats[n+c] = 0.f;
  }
}

// ---------------- final BN + ReLU (f32 out into d_out h region) ----------------
__global__ void bn_relu_final(const uint16_t* __restrict__ u, const float* __restrict__ scale,
                              const float* __restrict__ shift, float* __restrict__ hf){
  int i = blockIdx.x*256 + threadIdx.x;
  const int total2 = NN*EMB/2;
  if (i >= total2) return;
  uint32_t v = ((const uint32_t*)u)[i];
  int c = (i*2) % EMB;
  float f0 = fmaxf(bflo(v)*scale[c  ] + shift[c  ], 0.f);
  float f1 = fmaxf(bfhi(v)*scale[c+1] + shift[c+1], 0.f);
  ((float2*)hf)[i] = make_float2(f0, f1);
}

// ---------------- global add pool (batch sorted), h f32 in d_out ----------------
__global__ void pool_kernel(const float* __restrict__ h, const int* __restrict__ batch,
                            float* __restrict__ pool){
  __shared__ int bs[64];
  int c = threadIdx.x;
  int n0 = blockIdx.x*64;
  if (c < 64){ int i = n0 + c; bs[c] = (i < NN) ? batch[i] : -1; }
  __syncthreads();
  float sum = 0.f; int cur = -1;
  for (int tt=0; tt<64; tt++){
    int i = n0 + tt;
    if (i >= NN) break;
    int g = bs[tt];
    float v = h[(size_t)i*EMB + c];
    if (g != cur){
      if (cur >= 0) atomicAdd(&pool[(size_t)cur*EMB + c], sum);
      cur = g; sum = v;
    } else sum += v;
  }
  if (cur >= 0) atomicAdd(&pool[(size_t)cur*EMB + c], sum);
}
__global__ void pool_to_out(const float* __restrict__ pool, float* __restrict__ outp){
  int i = blockIdx.x*256 + threadIdx.x;
  if (i < 128*EMB) outp[i] = pool[i];
}

// ---------------- host orchestration ----------------
extern "C" void kernel_launch(void* const* d_in, const int* in_sizes, int n_in,
                              void* d_out, int out_size, void* d_ws, size_t ws_size,
                              hipStream_t stream){
  (void)in_sizes; (void)n_in; (void)out_size; (void)ws_size;
  const int* batch = (const int*)d_in[0];
  const int* x     = (const int*)d_in[1];
  const int* eidx  = (const int*)d_in[2];
  const int* eattr = (const int*)d_in[3];
  const float* aemb = (const float*)d_in[4];
  const float* bemb = (const float*)d_in[5];
  const float* W1 = (const float*)d_in[6];
  const float* b1 = (const float*)d_in[7];
  const float* g1 = (const float*)d_in[8];
  const float* be1= (const float*)d_in[9];
  const float* W2 = (const float*)d_in[10];
  const float* b2 = (const float*)d_in[11];
  const float* gbn= (const float*)d_in[12];
  const float* bbn= (const float*)d_in[13];
  float* out = (float*)d_out;   // [128*EMB graph_emb][NN*EMB h], both f32

  char* base = (char*)d_ws;
  size_t off = 0;
  auto alloc = [&](size_t bytes) -> void* {
    void* p = base + off;
    off = (off + bytes + 255) & ~(size_t)255;
    return p;
  };
  uint16_t* za   = (uint16_t*)alloc((size_t)NN*EMB*2);   // agg output (GEMM1 A)
  uint16_t* zm   = (uint16_t*)alloc((size_t)NN*EMB*2);   // atom-enc out / GEMM2 out
  uint16_t* t    = (uint16_t*)alloc((size_t)NN*NH*2);
  uint16_t* W1t  = (uint16_t*)alloc((size_t)NL*NH*EMB*2);
  uint16_t* W2t  = (uint16_t*)alloc((size_t)NL*EMB*NH*2);
  uint16_t* bondt= (uint16_t*)alloc((size_t)512*EMB*2);
  float* stats1  = (float*)alloc(NH*2*4);    // 6144 B, 256-aligned
  float* stats2  = (float*)alloc(EMB*2*4);   // 3072 B, contiguous after stats1
  float* scale1  = (float*)alloc(NH*4);
  float* shift1  = (float*)alloc(NH*4);
  float* scale2  = (float*)alloc(EMB*4);
  float* shift2  = (float*)alloc(EMB*4);
  float* pool    = (float*)alloc(128*EMB*4);
  int* count   = (int*)alloc((size_t)NN*4);
  int* rowptr  = (int*)alloc((size_t)(NN+1)*4);
  int* cursor  = (int*)alloc((size_t)NN*4);
  int* bsum    = (int*)alloc(256*4);
  int* csr_src = (int*)alloc((size_t)NE*4);
  int* csr_code= (int*)alloc((size_t)NE*4);

  const int* esrc = eidx;
  const int* edst = eidx + NE;
  const int nsb = (NN + 255)/256;

  hipMemsetAsync(count, 0, (size_t)NN*4, stream);
  hist_kernel<<<(NE+255)/256, 256, 0, stream>>>(edst, count);
  scan_block_sum<<<nsb, 256, 0, stream>>>(count, bsum, NN);
  scan_excl_small<<<1, 256, 0, stream>>>(bsum, nsb);
  scan_final<<<nsb, 256, 0, stream>>>(count, bsum, rowptr, cursor, NN);
  scatter_kernel<<<(NE+255)/256, 256, 0, stream>>>(edst, esrc, eattr, cursor, csr_src, csr_code);

  build_bond<<<512, 192, 0, stream>>>(bemb, bondt);
  transpose_w<<<dim3(NH/32, EMB/32, NL), dim3(32,32), 0, stream>>>(W1, W1t, EMB, NH);
  transpose_w<<<dim3(EMB/32, NH/32, NL), dim3(32,32), 0, stream>>>(W2, W2t, NH, EMB);

  atom_encode<<<NN/4, 256, 0, stream>>>(x, aemb, zm);
  hipMemsetAsync(pool, 0, (size_t)128*EMB*4, stream);
  // stats1 (6144B) + stats2 (3072B) contiguous: one clear; bn_finalize self-clears thereafter
  hipMemsetAsync(stats1, 0, (size_t)(6144 + 3072), stream);

  const int nbr = (NN + 127)/128;               // 391 row tiles
  const int nbrr = ((nbr + 7)/8)*8;             // 392 (XCD-swizzled)
  const int g1blocks = nbrr*(NH/128);           // 2352
  const int g2blocks = nbrr*(EMB/128);          // 1176
  for (int l = 0; l < NL; l++){
    if (l == 0)
      agg_kernel<0><<<NN/4, 256, 0, stream>>>(zm, bondt, nullptr, nullptr,
                                              rowptr, csr_src, csr_code, za);
    else
      agg_kernel<1><<<NN/4, 256, 0, stream>>>(zm, bondt, scale2, shift2,
                                              rowptr, csr_src, csr_code, za);
    gemm_bt<0, EMB><<<g1blocks, 256, 0, stream>>>(
        za, W1t + (size_t)l*NH*EMB, b1 + l*NH, nullptr, nullptr, t, stats1, NN, NH, nbr);
    bn_finalize<<<(NH+255)/256, 256, 0, stream>>>(stats1, g1 + l*NH, be1 + l*NH,
                                                  scale1, shift1, NH, 1.0f/NN);
    gemm_bt<1, NH><<<g2blocks, 256, 0, stream>>>(
        t, W2t + (size_t)l*EMB*NH, b2 + l*EMB, scale1, shift1, zm, stats2, NN, EMB, nbr);
    bn_finalize<<<(EMB+255)/256, 256, 0, stream>>>(stats2, gbn + l*EMB, bbn + l*EMB,
                                                   scale2, shift2, EMB, 1.0f/NN);
  }
  bn_relu_final<<<(NN*EMB/2 + 255)/256, 256, 0, stream>>>(zm, scale2, shift2, out + 128*EMB);
  pool_kernel<<<(NN+63)/64, 384, 0, stream>>>(out + 128*EMB, batch, pool);
  pool_to_out<<<(128*EMB+255)/256, 256, 0, stream>>>(pool, out);
}

// Round 13
// 1096.604 us; speedup vs baseline: 1.0994x; 1.0994x over previous
//
#include <hip/hip_runtime.h>
#include <stdint.h>

#define NN 50000
#define NE 400000
#define EMB 384
#define NH 768
#define NL 5

typedef __bf16 bf16x8_t __attribute__((ext_vector_type(8)));
typedef float  f32x4_t  __attribute__((ext_vector_type(4)));

__device__ __forceinline__ float bflo(uint32_t u){ union{uint32_t u;float f;} v; v.u = u<<16; return v.f; }
__device__ __forceinline__ float bfhi(uint32_t u){ union{uint32_t u;float f;} v; v.u = u & 0xffff0000u; return v.f; }
__device__ __forceinline__ uint16_t f2bf(float f){
  union{float f;uint32_t u;} v; v.f=f;
  uint32_t r = v.u + 0x7fffu + ((v.u>>16)&1u);
  return (uint16_t)(r>>16);
}
__device__ __forceinline__ uint32_t bfpack2(float a, float b){
  return (uint32_t)f2bf(a) | ((uint32_t)f2bf(b)<<16);
}
// hardware packed f32->bf16 (RTNE), 1 instruction for 2 elements — hot paths only
__device__ __forceinline__ uint32_t bfpack2h(float a, float b){
  uint32_t r;
  asm("v_cvt_pk_bf16_f32 %0, %1, %2" : "=v"(r) : "v"(a), "v"(b));
  return r;
}
__device__ __forceinline__ bf16x8_t as_bf16x8(uint4 u){
  union{uint4 a; bf16x8_t b;} c; c.a = u; return c.b;
}

// async global->LDS DMA, 16B per lane. LDS dest must be wave-uniform base + lane*16.
__device__ __forceinline__ void gld16(uint16_t* ldsp, const uint16_t* gp){
  __builtin_amdgcn_global_load_lds(
      (const __attribute__((address_space(1))) uint32_t*)gp,
      (__attribute__((address_space(3))) uint32_t*)ldsp,
      16, 0, 0);
}

// ---------------- CSR build ----------------
__global__ void hist_kernel(const int* __restrict__ dst, int* __restrict__ count){
  int i = blockIdx.x*256 + threadIdx.x;
  if (i < NE) atomicAdd(&count[dst[i]], 1);
}
__global__ void scan_block_sum(const int* __restrict__ count, int* __restrict__ bsum, int n){
  __shared__ int s[256];
  int i = blockIdx.x*256 + threadIdx.x;
  s[threadIdx.x] = (i<n) ? count[i] : 0;
  __syncthreads();
  for (int st=128; st>0; st>>=1){
    if (threadIdx.x < st) s[threadIdx.x] += s[threadIdx.x+st];
    __syncthreads();
  }
  if (threadIdx.x==0) bsum[blockIdx.x] = s[0];
}
__global__ void scan_excl_small(int* __restrict__ bsum, int nb){
  __shared__ int s[256];
  int t = threadIdx.x;
  int v = (t<nb) ? bsum[t] : 0;
  s[t] = v;
  __syncthreads();
  for (int st=1; st<256; st<<=1){
    int u = (t>=st) ? s[t-st] : 0;
    __syncthreads();
    s[t] += u;
    __syncthreads();
  }
  if (t<nb) bsum[t] = s[t] - v;
}
__global__ void scan_final(const int* __restrict__ count, const int* __restrict__ bsum,
                           int* __restrict__ rowptr, int* __restrict__ cursor, int n){
  __shared__ int s[256];
  int t = threadIdx.x;
  int i = blockIdx.x*256 + t;
  int v = (i<n) ? count[i] : 0;
  s[t] = v;
  __syncthreads();
  for (int st=1; st<256; st<<=1){
    int u = (t>=st) ? s[t-st] : 0;
    __syncthreads();
    s[t] += u;
    __syncthreads();
  }
  int off = bsum[blockIdx.x] + s[t] - v;
  if (i < n){
    rowptr[i] = off; cursor[i] = off;
    if (i == n-1) rowptr[n] = off + v;
  }
}
__global__ void scatter_kernel(const int* __restrict__ dst, const int* __restrict__ src,
                               const int* __restrict__ eattr, int* __restrict__ cursor,
                               int* __restrict__ csr_src, int* __restrict__ csr_code){
  int e = blockIdx.x*256 + threadIdx.x;
  if (e < NE){
    int p = atomicAdd(&cursor[dst[e]], 1);
    csr_src[p] = src[e];
    csr_code[p] = eattr[e*3] | (eattr[e*3+1]<<3) | (eattr[e*3+2]<<6);
  }
}

// ---------------- bond-sum table ----------------
__global__ void build_bond(const float* __restrict__ bemb, uint16_t* __restrict__ bt){
  const int code = blockIdx.x;            // 512
  const int t0 = code&7, t1=(code>>3)&7, t2=code>>6;
  const int c = threadIdx.x;              // 192 threads x 2 floats
  const float2 a = ((const float2*)(bemb + (size_t)( 0+t0)*EMB))[c];
  const float2 b = ((const float2*)(bemb + (size_t)( 8+t1)*EMB))[c];
  const float2 d = ((const float2*)(bemb + (size_t)(16+t2)*EMB))[c];
  ((uint32_t*)(bt + (size_t)code*EMB))[c] = bfpack2(a.x+b.x+d.x, a.y+b.y+d.y);
}

// ---------------- weight transpose + f32->bf16 ----------------
__global__ void transpose_w(const float* __restrict__ in, uint16_t* __restrict__ outp,
                            int R, int Cc){
  __shared__ float tile[32][33];
  const size_t lo = (size_t)blockIdx.z * R * Cc;
  int cb = blockIdx.x*32, rb = blockIdx.y*32;
  int r = rb + threadIdx.y, c = cb + threadIdx.x;
  if (r < R && c < Cc) tile[threadIdx.y][threadIdx.x] = in[lo + (size_t)r*Cc + c];
  __syncthreads();
  int orr = cb + threadIdx.y, occ = rb + threadIdx.x;
  if (orr < Cc && occ < R) outp[lo + (size_t)orr*R + occ] = f2bf(tile[threadIdx.x][threadIdx.y]);
}

// ---------------- atom encoder ----------------
__global__ __launch_bounds__(256) void atom_encode(
    const int* __restrict__ x, const float* __restrict__ aemb,
    uint16_t* __restrict__ h){
  const int w = threadIdx.x >> 6, lane = threadIdx.x & 63;
  const int i = blockIdx.x*4 + w;
  if (i >= NN) return;
  float a0=0,a1=0,a2=0,a3=0,a4=0,a5=0;
  #pragma unroll
  for (int k=0;k<9;k++){
    const int idx = x[i*9+k];
    const float2* p = (const float2*)(aemb + ((size_t)(k*64+idx))*EMB) + lane*3;
    float2 u0=p[0], u1=p[1], u2=p[2];
    a0+=u0.x; a1+=u0.y; a2+=u1.x; a3+=u1.y; a4+=u2.x; a5+=u2.y;
  }
  uint32_t* hp = (uint32_t*)(h + (size_t)i*EMB) + lane*3;
  hp[0]=bfpack2(a0,a1); hp[1]=bfpack2(a2,a3); hp[2]=bfpack2(a4,a5);
}

// ---------------- aggregation (static: one wave per node) ----------------
template<int BNREL>
__global__ __launch_bounds__(256) void agg_kernel(
    const uint16_t* __restrict__ in, const uint16_t* __restrict__ bondt,
    const float* __restrict__ scale, const float* __restrict__ shift,
    const int* __restrict__ rowptr, const int* __restrict__ csr_src,
    const int* __restrict__ csr_code, uint16_t* __restrict__ za){
  const int w = threadIdx.x >> 6, lane = threadIdx.x & 63;
  const int i = blockIdx.x*4 + w;
  if (i >= NN) return;

  float sc0=0,sc1=0,sc2=0,sc3=0,sc4=0,sc5=0, sh0=0,sh1=0,sh2=0,sh3=0,sh4=0,sh5=0;
  if (BNREL){
    const int c = lane*6;
    sc0=scale[c]; sc1=scale[c+1]; sc2=scale[c+2]; sc3=scale[c+3]; sc4=scale[c+4]; sc5=scale[c+5];
    sh0=shift[c]; sh1=shift[c+1]; sh2=shift[c+2]; sh3=shift[c+3]; sh4=shift[c+4]; sh5=shift[c+5];
  }

  const uint32_t* hs = (const uint32_t*)(in + (size_t)i*EMB) + lane*3;
  uint32_t s0=hs[0], s1=hs[1], s2=hs[2];
  float a0,a1,a2,a3,a4,a5;
  if (BNREL){
    a0 = fmaxf(bflo(s0)*sc0+sh0, 0.f); a1 = fmaxf(bfhi(s0)*sc1+sh1, 0.f);
    a2 = fmaxf(bflo(s1)*sc2+sh2, 0.f); a3 = fmaxf(bfhi(s1)*sc3+sh3, 0.f);
    a4 = fmaxf(bflo(s2)*sc4+sh4, 0.f); a5 = fmaxf(bfhi(s2)*sc5+sh5, 0.f);
  } else {
    a0 = bflo(s0); a1 = bfhi(s0); a2 = bflo(s1); a3 = bfhi(s1); a4 = bflo(s2); a5 = bfhi(s2);
  }

  const int rs = rowptr[i], re = rowptr[i+1];
  int k = rs;
  for (; k + 4 <= re; k += 4){
    int sj[4], cj[4];
    #pragma unroll
    for (int j=0;j<4;j++){ sj[j]=csr_src[k+j]; cj[j]=csr_code[k+j]; }
    uint32_t u[4][3], b[4][3];
    #pragma unroll
    for (int j=0;j<4;j++){
      const uint32_t* hp = (const uint32_t*)(in + (size_t)sj[j]*EMB) + lane*3;
      u[j][0]=hp[0]; u[j][1]=hp[1]; u[j][2]=hp[2];
      const uint32_t* bp = (const uint32_t*)(bondt + (size_t)cj[j]*EMB) + lane*3;
      b[j][0]=bp[0]; b[j][1]=bp[1]; b[j][2]=bp[2];
    }
    #pragma unroll
    for (int j=0;j<4;j++){
      float v0,v1,v2,v3,v4,v5;
      if (BNREL){
        v0 = fmaxf(bflo(u[j][0])*sc0+sh0, 0.f); v1 = fmaxf(bfhi(u[j][0])*sc1+sh1, 0.f);
        v2 = fmaxf(bflo(u[j][1])*sc2+sh2, 0.f); v3 = fmaxf(bfhi(u[j][1])*sc3+sh3, 0.f);
        v4 = fmaxf(bflo(u[j][2])*sc4+sh4, 0.f); v5 = fmaxf(bfhi(u[j][2])*sc5+sh5, 0.f);
      } else {
        v0=bflo(u[j][0]); v1=bfhi(u[j][0]); v2=bflo(u[j][1]);
        v3=bfhi(u[j][1]); v4=bflo(u[j][2]); v5=bfhi(u[j][2]);
      }
      a0 += fmaxf(v0+bflo(b[j][0]), 0.f); a1 += fmaxf(v1+bfhi(b[j][0]), 0.f);
      a2 += fmaxf(v2+bflo(b[j][1]), 0.f); a3 += fmaxf(v3+bfhi(b[j][1]), 0.f);
      a4 += fmaxf(v4+bflo(b[j][2]), 0.f); a5 += fmaxf(v5+bfhi(b[j][2]), 0.f);
    }
  }
  for (; k < re; k++){
    const int s = csr_src[k];
    const int code = csr_code[k];
    const uint32_t* hp = (const uint32_t*)(in + (size_t)s*EMB) + lane*3;
    uint32_t u0=hp[0], u1=hp[1], u2=hp[2];
    const uint32_t* bp = (const uint32_t*)(bondt + (size_t)code*EMB) + lane*3;
    uint32_t b0=bp[0], b1=bp[1], b2=bp[2];
    float v0,v1,v2,v3,v4,v5;
    if (BNREL){
      v0 = fmaxf(bflo(u0)*sc0+sh0, 0.f); v1 = fmaxf(bfhi(u0)*sc1+sh1, 0.f);
      v2 = fmaxf(bflo(u1)*sc2+sh2, 0.f); v3 = fmaxf(bfhi(u1)*sc3+sh3, 0.f);
      v4 = fmaxf(bflo(u2)*sc4+sh4, 0.f); v5 = fmaxf(bfhi(u2)*sc5+sh5, 0.f);
    } else {
      v0=bflo(u0); v1=bfhi(u0); v2=bflo(u1); v3=bfhi(u1); v4=bflo(u2); v5=bfhi(u2);
    }
    a0 += fmaxf(v0+bflo(b0), 0.f); a1 += fmaxf(v1+bfhi(b0), 0.f);
    a2 += fmaxf(v2+bflo(b1), 0.f); a3 += fmaxf(v3+bfhi(b1), 0.f);
    a4 += fmaxf(v4+bflo(b2), 0.f); a5 += fmaxf(v5+bfhi(b2), 0.f);
  }

  uint32_t* zp = (uint32_t*)(za + (size_t)i*EMB) + lane*3;
  zp[0] = bfpack2(a0,a1);
  zp[1] = bfpack2(a2,a3);
  zp[2] = bfpack2(a4,a5);
}

// ---------------- GEMM: r8 structure VERBATIM (best measured: 1128 µs) + T5 setprio ----
// 12-round conclusion: r9 (bigger parts), r10 (deeper A prefetch), r12 (3-buf counted
// vmcnt) ALL regressed by exactly the occupancy they cost — inter-block TLP is the latency
// hider at 2-3 blocks/CU. r8 is the measured optimum of this family. This round reverts to
// it byte-for-byte and adds the only zero-resource lever left: s_setprio(1) around the MFMA
// cluster (T5). Waves here have role diversity (barrier-free within part: DMA-issue /
// A-load / transform / MFMA, across 2-3 blocks) — the regime where T5 paid on 8-phase GEMM.
// Revert markers expected: LDS 33792/39936, VGPR 60/68, WRITE exactly 77346/38673.
template<int BNA, int KK>
__global__ __launch_bounds__(256, 2) void gemm_bt(
    const uint16_t* __restrict__ A, const uint16_t* __restrict__ Bt,
    const float* __restrict__ bias, const float* __restrict__ scA,
    const float* __restrict__ shA, uint16_t* __restrict__ C,
    float* __restrict__ stats, int M, int N, int nbr){
  constexpr int NK = KK/32;        // 12 or 24 kq steps
  constexpr int NPART = NK/2;      // 6 or 12 parts of 64-K
  __shared__ __align__(16) uint16_t panel[2][1024*8];   // 2 x 16KB: slot gidx = 16B
  __shared__ float sAs[BNA ? KK : 1];
  __shared__ float hAs[BNA ? KK : 1];
  __shared__ float csum[128];
  __shared__ float csq[128];

  const int tid = threadIdx.x;
  const int nbc = N >> 7;
  const int xcd = blockIdx.x & 7;
  const int slot = blockIdx.x >> 3;
  const int bcol = slot % nbc;
  const int brow = (slot / nbc)*8 + xcd;
  if (brow >= nbr) return;
  const int rowbase = brow << 7;

  const int lane = tid & 63;
  const int w = tid >> 6;
  const int quad = lane >> 4, l16 = lane & 15;
  const int bcol128 = bcol*128;

  // A per-lane rows: wave w owns rows w*32..+31; frag mi adds 16
  int rowA0 = rowbase + w*32 + l16;      if (rowA0 >= M) rowA0 = M-1;
  int rowA1 = rowbase + w*32 + 16 + l16; if (rowA1 >= M) rowA1 = M-1;
  const uint16_t* gA0 = A + (size_t)rowA0*KK + quad*8;
  const uint16_t* gA1 = A + (size_t)rowA1*KK + quad*8;

  if (BNA){
    for (int i = tid; i < KK; i += 256){ sAs[i] = scA[i]; hAs[i] = shA[i]; }
  }

  // coalesced pre-swizzled DMA: slot gidx <- Bt[col=gidx>>3][k0 + ((gidx&7)^((gidx>>5)&7))*8]
  auto stageB = [&](int buf, int k0){
    #pragma unroll
    for (int c = 0; c < 4; ++c){
      const int gidx = c*256 + tid;
      const int col  = gidx >> 3;
      const int k8   = (gidx & 7) ^ ((gidx >> 5) & 7);
      gld16(&panel[buf][(size_t)gidx*8],
            Bt + (size_t)(bcol128 + col)*KK + k0 + k8*8);
    }
  };
  // BN+ReLU transform of an A fragment (in-register, off all sync paths)
  auto xf = [&](uint4 ca, int kq)->bf16x8_t{
    const int kb = kq*32 + quad*8;
    float4 sv0 = *(const float4*)&sAs[kb];
    float4 sv1 = *(const float4*)&sAs[kb+4];
    float4 hv0 = *(const float4*)&hAs[kb];
    float4 hv1 = *(const float4*)&hAs[kb+4];
    float e0,e1,e2,e3,e4,e5,e6,e7;
    e0=fmaxf(bflo(ca.x)*sv0.x+hv0.x,0.f); e1=fmaxf(bfhi(ca.x)*sv0.y+hv0.y,0.f);
    e2=fmaxf(bflo(ca.y)*sv0.z+hv0.z,0.f); e3=fmaxf(bfhi(ca.y)*sv0.w+hv0.w,0.f);
    e4=fmaxf(bflo(ca.z)*sv1.x+hv1.x,0.f); e5=fmaxf(bfhi(ca.z)*sv1.y+hv1.y,0.f);
    e6=fmaxf(bflo(ca.w)*sv1.z+hv1.z,0.f); e7=fmaxf(bfhi(ca.w)*sv1.w+hv1.w,0.f);
    return as_bf16x8(make_uint4(bfpack2h(e0,e1),bfpack2h(e2,e3),bfpack2h(e4,e5),bfpack2h(e6,e7)));
  };

  f32x4_t acc[2][2][4];
  #pragma unroll
  for (int mi=0;mi<2;mi++)
    #pragma unroll
    for (int g=0;g<2;g++)
      #pragma unroll
      for (int nj=0;nj<4;nj++)
        acc[mi][g][nj] = (f32x4_t){0.f,0.f,0.f,0.f};

  auto mf = [&](int buf, int s, bf16x8_t fa0, bf16x8_t fa1){
    const int lx = (s*4 + quad) ^ (l16 & 7);
    __builtin_amdgcn_s_setprio(1);        // T5: favor this wave while MFMA cluster issues
    #pragma unroll
    for (int g=0; g<2; ++g)
      #pragma unroll
      for (int nj=0; nj<4; ++nj){
        const int col = g*64 + l16*4 + nj;
        bf16x8_t fb = *(const bf16x8_t*)&panel[buf][(size_t)(col*8 + lx)*8];
        acc[0][g][nj] = __builtin_amdgcn_mfma_f32_16x16x32_bf16(fa0, fb, acc[0][g][nj], 0,0,0);
        acc[1][g][nj] = __builtin_amdgcn_mfma_f32_16x16x32_bf16(fa1, fb, acc[1][g][nj], 0,0,0);
      }
    __builtin_amdgcn_s_setprio(0);
  };

  // ---- prologue: DMA part 0, A kq0/kq1 into named scalars ----
  stageB(0, 0);
  uint4 a0c = *(const uint4*)(gA0);
  uint4 a1c = *(const uint4*)(gA1);
  uint4 a0n = *(const uint4*)(gA0 + 32);
  uint4 a1n = *(const uint4*)(gA1 + 32);
  __syncthreads();                        // panel[0] + sAs ready

  for (int p = 0; p < NPART; ++p){
    if (p + 1 < NPART) stageB((p+1)&1, (p+1)*64);   // DMA next part into other buffer
    // s = 0 : kq = 2p (uses a0c/a1c, then reloads them for kq+2)
    {
      const int kq = 2*p;
      bf16x8_t fa0 = BNA ? xf(a0c, kq) : as_bf16x8(a0c);
      bf16x8_t fa1 = BNA ? xf(a1c, kq) : as_bf16x8(a1c);
      if (kq + 2 < NK){
        a0c = *(const uint4*)(gA0 + (kq+2)*32);
        a1c = *(const uint4*)(gA1 + (kq+2)*32);
      }
      mf(p&1, 0, fa0, fa1);
    }
    // s = 1 : kq = 2p+1 (uses a0n/a1n, then reloads them for kq+2)
    {
      const int kq = 2*p + 1;
      bf16x8_t fa0 = BNA ? xf(a0n, kq) : as_bf16x8(a0n);
      bf16x8_t fa1 = BNA ? xf(a1n, kq) : as_bf16x8(a1n);
      if (kq + 2 < NK){
        a0n = *(const uint4*)(gA0 + (kq+2)*32);
        a1n = *(const uint4*)(gA1 + (kq+2)*32);
      }
      mf(p&1, 1, fa0, fa1);
    }
    __syncthreads();   // all waves done with panel[p&1]; next part's DMA drained
  }

  if (tid < 128){ csum[tid]=0.f; csq[tid]=0.f; }
  __syncthreads();

  const int colbase = bcol128 + l16*4;
  float bv[2][4], ssum[2][4], sq[2][4];
  #pragma unroll
  for (int g=0;g<2;g++)
    #pragma unroll
    for (int nj=0;nj<4;nj++){
      bv[g][nj] = bias[colbase + g*64 + nj];
      ssum[g][nj] = 0.f; sq[g][nj] = 0.f;
    }

  #pragma unroll
  for (int mi=0;mi<2;mi++){
    #pragma unroll
    for (int r=0;r<4;r++){
      const int grow = rowbase + w*32 + mi*16 + quad*4 + r;
      if (grow < M){
        #pragma unroll
        for (int g=0;g<2;g++){
          float v0 = acc[mi][g][0][r] + bv[g][0];
          float v1 = acc[mi][g][1][r] + bv[g][1];
          float v2 = acc[mi][g][2][r] + bv[g][2];
          float v3 = acc[mi][g][3][r] + bv[g][3];
          uint2 pk = make_uint2(bfpack2h(v0,v1), bfpack2h(v2,v3));
          *(uint2*)(C + (size_t)grow*N + colbase + g*64) = pk;
          ssum[g][0]+=v0; ssum[g][1]+=v1; ssum[g][2]+=v2; ssum[g][3]+=v3;
          sq[g][0]+=v0*v0; sq[g][1]+=v1*v1; sq[g][2]+=v2*v2; sq[g][3]+=v3*v3;
        }
      }
    }
  }
  #pragma unroll
  for (int g=0;g<2;g++)
    #pragma unroll
    for (int nj=0;nj<4;nj++){
      ssum[g][nj] += __shfl_xor(ssum[g][nj], 16); ssum[g][nj] += __shfl_xor(ssum[g][nj], 32);
      sq[g][nj]   += __shfl_xor(sq[g][nj],   16); sq[g][nj]   += __shfl_xor(sq[g][nj],   32);
    }
  if (quad == 0){
    #pragma unroll
    for (int g=0;g<2;g++)
      #pragma unroll
      for (int nj=0;nj<4;nj++){
        atomicAdd(&csum[g*64 + l16*4 + nj], ssum[g][nj]);
        atomicAdd(&csq [g*64 + l16*4 + nj], sq[g][nj]);
      }
  }
  __syncthreads();
  if (tid < 128){
    atomicAdd(&stats[bcol128 + tid], csum[tid]);
    atomicAdd(&stats[N + bcol128 + tid], csq[tid]);
  }
}

// ---------------- BN finalize (self-clearing) ----------------
__global__ void bn_finalize(float* __restrict__ stats, const float* __restrict__ gamma,
                            const float* __restrict__ beta, float* __restrict__ scale,
                            float* __restrict__ shift, int n, float invM){
  int c = blockIdx.x*256 + threadIdx.x;
  if (c < n){
    float mean = stats[c]*invM;
    float var  = stats[n+c]*invM - mean*mean;
    float sc = gamma[c] * rsqrtf(var + 1e-5f);
    scale[c] = sc;
    shift[c] = beta[c] - mean*sc;
    stats[c] = 0.f;
    stats[n+c] = 0.f;
  }
}

// ---------------- final BN + ReLU (f32 out into d_out h region) ----------------
__global__ void bn_relu_final(const uint16_t* __restrict__ u, const float* __restrict__ scale,
                              const float* __restrict__ shift, float* __restrict__ hf){
  int i = blockIdx.x*256 + threadIdx.x;
  const int total2 = NN*EMB/2;
  if (i >= total2) return;
  uint32_t v = ((const uint32_t*)u)[i];
  int c = (i*2) % EMB;
  float f0 = fmaxf(bflo(v)*scale[c  ] + shift[c  ], 0.f);
  float f1 = fmaxf(bfhi(v)*scale[c+1] + shift[c+1], 0.f);
  ((float2*)hf)[i] = make_float2(f0, f1);
}

// ---------------- global add pool (batch sorted), h f32 in d_out ----------------
__global__ void pool_kernel(const float* __restrict__ h, const int* __restrict__ batch,
                            float* __restrict__ pool){
  __shared__ int bs[64];
  int c = threadIdx.x;
  int n0 = blockIdx.x*64;
  if (c < 64){ int i = n0 + c; bs[c] = (i < NN) ? batch[i] : -1; }
  __syncthreads();
  float sum = 0.f; int cur = -1;
  for (int tt=0; tt<64; tt++){
    int i = n0 + tt;
    if (i >= NN) break;
    int g = bs[tt];
    float v = h[(size_t)i*EMB + c];
    if (g != cur){
      if (cur >= 0) atomicAdd(&pool[(size_t)cur*EMB + c], sum);
      cur = g; sum = v;
    } else sum += v;
  }
  if (cur >= 0) atomicAdd(&pool[(size_t)cur*EMB + c], sum);
}
__global__ void pool_to_out(const float* __restrict__ pool, float* __restrict__ outp){
  int i = blockIdx.x*256 + threadIdx.x;
  if (i < 128*EMB) outp[i] = pool[i];
}

// ---------------- host orchestration ----------------
extern "C" void kernel_launch(void* const* d_in, const int* in_sizes, int n_in,
                              void* d_out, int out_size, void* d_ws, size_t ws_size,
                              hipStream_t stream){
  (void)in_sizes; (void)n_in; (void)out_size; (void)ws_size;
  const int* batch = (const int*)d_in[0];
  const int* x     = (const int*)d_in[1];
  const int* eidx  = (const int*)d_in[2];
  const int* eattr = (const int*)d_in[3];
  const float* aemb = (const float*)d_in[4];
  const float* bemb = (const float*)d_in[5];
  const float* W1 = (const float*)d_in[6];
  const float* b1 = (const float*)d_in[7];
  const float* g1 = (const float*)d_in[8];
  const float* be1= (const float*)d_in[9];
  const float* W2 = (const float*)d_in[10];
  const float* b2 = (const float*)d_in[11];
  const float* gbn= (const float*)d_in[12];
  const float* bbn= (const float*)d_in[13];
  float* out = (float*)d_out;   // [128*EMB graph_emb][NN*EMB h], both f32

  char* base = (char*)d_ws;
  size_t off = 0;
  auto alloc = [&](size_t bytes) -> void* {
    void* p = base + off;
    off = (off + bytes + 255) & ~(size_t)255;
    return p;
  };
  uint16_t* za   = (uint16_t*)alloc((size_t)NN*EMB*2);   // agg output (GEMM1 A)
  uint16_t* zm   = (uint16_t*)alloc((size_t)NN*EMB*2);   // atom-enc out / GEMM2 out
  uint16_t* t    = (uint16_t*)alloc((size_t)NN*NH*2);
  uint16_t* W1t  = (uint16_t*)alloc((size_t)NL*NH*EMB*2);
  uint16_t* W2t  = (uint16_t*)alloc((size_t)NL*EMB*NH*2);
  uint16_t* bondt= (uint16_t*)alloc((size_t)512*EMB*2);
  float* stats1  = (float*)alloc(NH*2*4);    // 6144 B, 256-aligned
  float* stats2  = (float*)alloc(EMB*2*4);   // 3072 B, contiguous after stats1
  float* scale1  = (float*)alloc(NH*4);
  float* shift1  = (float*)alloc(NH*4);
  float* scale2  = (float*)alloc(EMB*4);
  float* shift2  = (float*)alloc(EMB*4);
  float* pool    = (float*)alloc(128*EMB*4);
  int* count   = (int*)alloc((size_t)NN*4);
  int* rowptr  = (int*)alloc((size_t)(NN+1)*4);
  int* cursor  = (int*)alloc((size_t)NN*4);
  int* bsum    = (int*)alloc(256*4);
  int* csr_src = (int*)alloc((size_t)NE*4);
  int* csr_code= (int*)alloc((size_t)NE*4);

  const int* esrc = eidx;
  const int* edst = eidx + NE;
  const int nsb = (NN + 255)/256;

  hipMemsetAsync(count, 0, (size_t)NN*4, stream);
  hist_kernel<<<(NE+255)/256, 256, 0, stream>>>(edst, count);
  scan_block_sum<<<nsb, 256, 0, stream>>>(count, bsum, NN);
  scan_excl_small<<<1, 256, 0, stream>>>(bsum, nsb);
  scan_final<<<nsb, 256, 0, stream>>>(count, bsum, rowptr, cursor, NN);
  scatter_kernel<<<(NE+255)/256, 256, 0, stream>>>(edst, esrc, eattr, cursor, csr_src, csr_code);

  build_bond<<<512, 192, 0, stream>>>(bemb, bondt);
  transpose_w<<<dim3(NH/32, EMB/32, NL), dim3(32,32), 0, stream>>>(W1, W1t, EMB, NH);
  transpose_w<<<dim3(EMB/32, NH/32, NL), dim3(32,32), 0, stream>>>(W2, W2t, NH, EMB);

  atom_encode<<<NN/4, 256, 0, stream>>>(x, aemb, zm);
  hipMemsetAsync(pool, 0, (size_t)128*EMB*4, stream);
  // stats1 (6144B) + stats2 (3072B) contiguous: one clear; bn_finalize self-clears thereafter
  hipMemsetAsync(stats1, 0, (size_t)(6144 + 3072), stream);

  const int nbr = (NN + 127)/128;               // 391 row tiles
  const int nbrr = ((nbr + 7)/8)*8;             // 392 (XCD-swizzled)
  const int g1blocks = nbrr*(NH/128);           // 2352
  const int g2blocks = nbrr*(EMB/128);          // 1176
  for (int l = 0; l < NL; l++){
    if (l == 0)
      agg_kernel<0><<<NN/4, 256, 0, stream>>>(zm, bondt, nullptr, nullptr,
                                              rowptr, csr_src, csr_code, za);
    else
      agg_kernel<1><<<NN/4, 256, 0, stream>>>(zm, bondt, scale2, shift2,
                                              rowptr, csr_src, csr_code, za);
    gemm_bt<0, EMB><<<g1blocks, 256, 0, stream>>>(
        za, W1t + (size_t)l*NH*EMB, b1 + l*NH, nullptr, nullptr, t, stats1, NN, NH, nbr);
    bn_finalize<<<(NH+255)/256, 256, 0, stream>>>(stats1, g1 + l*NH, be1 + l*NH,
                                                  scale1, shift1, NH, 1.0f/NN);
    gemm_bt<1, NH><<<g2blocks, 256, 0, stream>>>(
        t, W2t + (size_t)l*EMB*NH, b2 + l*EMB, scale1, shift1, zm, stats2, NN, EMB, nbr);
    bn_finalize<<<(EMB+255)/256, 256, 0, stream>>>(stats2, gbn + l*EMB, bbn + l*EMB,
                                                   scale2, shift2, EMB, 1.0f/NN);
  }
  bn_relu_final<<<(NN*EMB/2 + 255)/256, 256, 0, stream>>>(zm, scale2, shift2, out + 128*EMB);
  pool_kernel<<<(NN+63)/64, 384, 0, stream>>>(out + 128*EMB, batch, pool);
  pool_to_out<<<(128*EMB+255)/256, 256, 0, stream>>>(pool, out);
}